// Round 1
// baseline (193.769 us; speedup 1.0000x reference)
//
#include <hip/hip_runtime.h>
#include <hip/hip_bf16.h>

// Self-guided-filter loss, fully fused per 32x32 tile.
// shapes fixed by reference: (8,3,512,512) fp32, RADIUS=5 (k=11), EPS=1e-6.
//
// Per block: one 32x32 output tile of one plane; the 3 images are processed
// sequentially reusing the same LDS buffers; per-pixel filtered values are
// kept in registers; block emits one fp32 partial sum. A final 1-block kernel
// sums the 6144 partials in double (deterministic) and scales by 1/N.

#define TB 32
#define INS 52          // TB + 2*10 (two nested radius-5 stages)
#define M1 42           // TB + 2*5  (a/b region)
#define XS_STRIDE 53
#define H1_STRIDE 43
#define AB_STRIDE 43
#define H2_STRIDE 33

// LDS float offsets (aliasing: xs -> mean/a -> boxa/boxb; h1x -> h2a; h1x2 -> h2b)
#define OFF_A   0       // 52*53 = 2756 floats
#define OFF_H1X 2756    // 52*43 = 2236
#define OFF_H1Y 4992    // 52*43 = 2236
#define OFF_B   7228    // 42*43 = 1806
#define S_FLOATS 9034   // 36,136 bytes -> 4 blocks/CU by LDS

#define NPLANES 24      // 8*3
#define WIDTH 512
#define NBLK_X 16
#define NBLK_Y 16
#define NPARTIALS (NBLK_X * NBLK_Y * NPLANES)   // 6144
#define TOTAL_ELEMS 6291456.0                   // 8*3*512*512

__global__ __launch_bounds__(256) void sgf_loss_kernel(
    const float* __restrict__ gen, const float* __restrict__ ir,
    const float* __restrict__ vi, float* __restrict__ partials)
{
    __shared__ float S[S_FLOATS];
    const int tid = threadIdx.x;
    const int tx0 = blockIdx.x * TB;
    const int ty0 = blockIdx.y * TB;
    const size_t pbase = (size_t)blockIdx.z * (WIDTH * WIDTH);
    const float inv121 = 1.0f / 121.0f;

    float fout[3][4];
    const float* imgs[3] = {gen, ir, vi};

    #pragma unroll
    for (int img = 0; img < 3; ++img) {
        const float* __restrict__ X = imgs[img] + pbase;

        __syncthreads();  // buffers may still be read by previous iteration / init no-op

        // P1: load xs tile (52x52) with zero padding at plane borders
        for (int i = tid; i < INS * INS; i += 256) {
            int r = i / INS, c = i % INS;
            int gy = ty0 - 10 + r, gx = tx0 - 10 + c;
            float v = 0.0f;
            if ((unsigned)gy < (unsigned)WIDTH && (unsigned)gx < (unsigned)WIDTH)
                v = X[gy * WIDTH + gx];
            S[OFF_A + r * XS_STRIDE + c] = v;
        }
        __syncthreads();

        // P2: horizontal 11-tap running sums of x and x^2 : h1[52][42]
        // tasks: 52 rows x 4 col-chunks (11,11,10,10) = 208
        if (tid < 208) {
            int r = tid >> 2, ch = tid & 3;
            int c0 = (ch < 2) ? ch * 11 : 22 + (ch - 2) * 10;
            int len = (ch < 2) ? 11 : 10;
            const float* row = &S[OFF_A + r * XS_STRIDE];
            float sx = 0.0f, sx2 = 0.0f;
            #pragma unroll
            for (int d = 0; d < 10; ++d) { float v = row[c0 + d]; sx += v; sx2 += v * v; }
            for (int j = 0; j < len; ++j) {
                int c = c0 + j;
                float vn = row[c + 10]; sx += vn; sx2 += vn * vn;
                S[OFF_H1X + r * H1_STRIDE + c] = sx;
                S[OFF_H1Y + r * H1_STRIDE + c] = sx2;
                float vo = row[c]; sx -= vo; sx2 -= vo * vo;
            }
        }
        __syncthreads();

        // P4: vertical 11-tap running sums -> mean (OFF_A), corr (OFF_B), * 1/121
        // tasks: 42 cols x 2 bufs x 2 row-chunks(21) = 168
        if (tid < 168) {
            int buf = tid & 1; int t2 = tid >> 1;
            int chunk = t2 & 1; int c = t2 >> 1;      // 0..41
            int r0 = chunk * 21;
            const float* src = &S[buf ? OFF_H1Y : OFF_H1X];
            float* dst = &S[buf ? OFF_B : OFF_A];
            float s = 0.0f;
            #pragma unroll
            for (int d = 0; d < 10; ++d) s += src[(r0 + d) * H1_STRIDE + c];
            for (int j = 0; j < 21; ++j) {
                int r = r0 + j;
                s += src[(r + 10) * H1_STRIDE + c];
                dst[r * AB_STRIDE + c] = s * inv121;
                s -= src[r * H1_STRIDE + c];
            }
        }
        __syncthreads();

        // P5: pointwise a,b in place; ZERO at plane-OOB (reference zero-pads a,b)
        for (int i = tid; i < M1 * M1; i += 256) {
            int r = i / M1, c = i % M1;
            int gy = ty0 - 5 + r, gx = tx0 - 5 + c;
            float A = 0.0f, B = 0.0f;
            if ((unsigned)gy < (unsigned)WIDTH && (unsigned)gx < (unsigned)WIDTH) {
                float m  = S[OFF_A + r * AB_STRIDE + c];
                float co = S[OFF_B + r * AB_STRIDE + c];
                float var = co - m * m;
                A = var / (var + 1e-6f);
                B = m - A * m;
            }
            S[OFF_A + r * AB_STRIDE + c] = A;
            S[OFF_B + r * AB_STRIDE + c] = B;
        }
        __syncthreads();

        // P6: horizontal 11-tap on a,b -> h2a (OFF_H1X, stride 33), h2b (OFF_H1Y)
        // tasks: 42 rows x 2 bufs x 2 col-chunks(16) = 168
        if (tid < 168) {
            int buf = tid & 1; int t2 = tid >> 1;
            int ch = t2 & 1; int r = t2 >> 1;        // 0..41
            int c0 = ch * 16;
            const float* src = &S[(buf ? OFF_B : OFF_A) + r * AB_STRIDE];
            float* dst = &S[(buf ? OFF_H1Y : OFF_H1X) + r * H2_STRIDE];
            float s = 0.0f;
            #pragma unroll
            for (int d = 0; d < 10; ++d) s += src[c0 + d];
            for (int j = 0; j < 16; ++j) {
                int c = c0 + j;
                s += src[c + 10];
                dst[c] = s;
                s -= src[c];
            }
        }
        __syncthreads();

        // P7: vertical 11-tap on h2 -> boxa (OFF_A+0), boxb (OFF_A+1056), * 1/121
        // tasks: 32 cols x 2 bufs x 4 row-chunks(8) = 256 exactly
        {
            int buf = tid & 1; int t2 = tid >> 1;
            int ch = t2 & 3; int c = t2 >> 2;        // 0..31
            int r0 = ch * 8;
            const float* src = &S[buf ? OFF_H1Y : OFF_H1X];
            float* dst = &S[OFF_A + (buf ? 1056 : 0)];
            float s = 0.0f;
            #pragma unroll
            for (int d = 0; d < 10; ++d) s += src[(r0 + d) * H2_STRIDE + c];
            #pragma unroll
            for (int j = 0; j < 8; ++j) {
                int r = r0 + j;
                s += src[(r + 10) * H2_STRIDE + c];
                dst[r * H2_STRIDE + c] = s * inv121;
                s -= src[r * H2_STRIDE + c];
            }
        }
        __syncthreads();

        // P8: f = x - (boxa*x + boxb) for this thread's 4 pixels
        #pragma unroll
        for (int k = 0; k < 4; ++k) {
            int p = tid + k * 256;
            int r = p >> 5, c = p & 31;
            float ba = S[OFF_A + r * H2_STRIDE + c];
            float bb = S[OFF_A + 1056 + r * H2_STRIDE + c];
            float x = X[(size_t)(ty0 + r) * WIDTH + (tx0 + c)];
            fout[img][k] = x - (ba * x + bb);
        }
    }

    // combine: |gen_f - max(|ir_f|,|vi_f|)|
    float acc = 0.0f;
    #pragma unroll
    for (int k = 0; k < 4; ++k) {
        float flit = fmaxf(fabsf(fout[1][k]), fabsf(fout[2][k]));
        acc += fabsf(fout[0][k] - flit);
    }

    // block reduction: wave shuffle then LDS across the 4 waves
    #pragma unroll
    for (int off = 32; off > 0; off >>= 1) acc += __shfl_down(acc, off);
    __syncthreads();               // all P8 LDS reads done before reuse
    if ((tid & 63) == 0) S[tid >> 6] = acc;
    __syncthreads();
    if (tid == 0) {
        float blocksum = S[0] + S[1] + S[2] + S[3];
        partials[((blockIdx.z * NBLK_Y) + blockIdx.y) * NBLK_X + blockIdx.x] = blocksum;
    }
}

__global__ __launch_bounds__(256) void sgf_final_reduce(
    const float* __restrict__ partials, float* __restrict__ out)
{
    __shared__ double sd[256];
    int tid = threadIdx.x;
    double s = 0.0;
    for (int i = tid; i < NPARTIALS; i += 256) s += (double)partials[i];
    sd[tid] = s;
    __syncthreads();
    for (int off = 128; off > 0; off >>= 1) {
        if (tid < off) sd[tid] += sd[tid + off];
        __syncthreads();
    }
    if (tid == 0) out[0] = (float)(sd[0] * (1.0 / TOTAL_ELEMS));
}

extern "C" void kernel_launch(void* const* d_in, const int* in_sizes, int n_in,
                              void* d_out, int out_size, void* d_ws, size_t ws_size,
                              hipStream_t stream) {
    const float* gen = (const float*)d_in[0];
    const float* ir  = (const float*)d_in[1];
    const float* vi  = (const float*)d_in[2];
    float* partials = (float*)d_ws;   // needs 6144 floats = 24 KB

    dim3 grid(NBLK_X, NBLK_Y, NPLANES);
    sgf_loss_kernel<<<grid, dim3(256), 0, stream>>>(gen, ir, vi, partials);
    sgf_final_reduce<<<1, dim3(256), 0, stream>>>(partials, (float*)d_out);
}

// Round 2
// 134.938 us; speedup vs baseline: 1.4360x; 1.4360x over previous
//
#include <hip/hip_runtime.h>
#include <hip/hip_bf16.h>

// Self-guided-filter loss, fused per 32x32 tile, fully vectorized LDS (b128).
// (8,3,512,512) fp32, RADIUS=5 (k=11), EPS=1e-6.
//
// Per block: one 32x32 tile of one plane; 3 images sequential, shared LDS.
// Stage-1 horizontal reads GLOBAL directly (L2-resident halo), writes h1 sums.
// All vertical passes are register running sums over vec4 columns.
// flit kept in LDS F across images. Deterministic two-kernel reduction.

#define W 512
#define TB 32
#define H1STR 48   // h1: 52 rows (img rows ty0-10+r), cols 0..41 valid, unnormalized 11-col sums
#define ABSTR 44   // A,B: 42 rows (img rows ty0-5+q), cols 0..41 valid (img col tx0-5+c)
#define H2STR 36   // h2: 42 rows, cols 0..31 (img col tx0+j), unnormalized 11-col sums of A/B
#define FSTR  36

#define O_H1X 0
#define O_H1Y 2496
#define O_A   4992
#define O_B   6840
#define O_H2A 0      // aliases H1X (h1 dead by P6)
#define O_H2B 2496   // aliases H1Y
#define O_F   8688
#define S_FLOATS 9840  // 39,360 B -> 4 blocks/CU

#define NBLK_X 16
#define NBLK_Y 16
#define NPLANES 24
#define NPARTIALS (NBLK_X*NBLK_Y*NPLANES)
#define TOTAL_ELEMS 6291456.0
#define INV121 (1.0f/121.0f)

__global__ __launch_bounds__(256, 4) void sgf_loss_kernel(
    const float* __restrict__ gen, const float* __restrict__ ir,
    const float* __restrict__ vi, float* __restrict__ partials)
{
    __shared__ __align__(16) float S[S_FLOATS];
    const int tid = threadIdx.x;
    const int tx0 = blockIdx.x * TB;
    const int ty0 = blockIdx.y * TB;
    const size_t pbase = (size_t)blockIdx.z * (W * W);

    float acc = 0.0f;

    #pragma unroll 1
    for (int img = 0; img < 3; ++img) {
        const float* __restrict__ X =
            (img == 0 ? ir : (img == 1 ? vi : gen)) + pbase;

        __syncthreads();   // region1 (H2/h1) reused across phases/images

        // ---- P2: global -> h1 horizontal 11-sums of x and x^2.
        // tasks: 52 rows x 6 col-groups of 8 = 312. h1 col j window = img cols tx0-10+j .. tx0+j.
        for (int t = tid; t < 312; t += 256) {
            int r = t / 6, cg = t - r * 6;
            int j0 = cg * 8;
            float* hx = &S[O_H1X + r * H1STR + j0];
            float* hy = &S[O_H1Y + r * H1STR + j0];
            int gy = ty0 - 10 + r;
            if ((unsigned)gy >= (unsigned)W) {
                float4 z = make_float4(0.f, 0.f, 0.f, 0.f);
                *(float4*)hx = z; *(float4*)(hx + 4) = z;
                *(float4*)hy = z; *(float4*)(hy + 4) = z;
                continue;
            }
            const float* Xr = X + (size_t)gy * W;
            int gx0 = tx0 - 12 + j0;           // 16B-aligned (tx0%4==0)
            float w[20];
            if (gx0 >= 0 && gx0 + 20 <= W) {
                const float4* p = (const float4*)(Xr + gx0);
                float4 v0 = p[0], v1 = p[1], v2 = p[2], v3 = p[3], v4 = p[4];
                w[0]=v0.x;  w[1]=v0.y;  w[2]=v0.z;  w[3]=v0.w;
                w[4]=v1.x;  w[5]=v1.y;  w[6]=v1.z;  w[7]=v1.w;
                w[8]=v2.x;  w[9]=v2.y;  w[10]=v2.z; w[11]=v2.w;
                w[12]=v3.x; w[13]=v3.y; w[14]=v3.z; w[15]=v3.w;
                w[16]=v4.x; w[17]=v4.y; w[18]=v4.z; w[19]=v4.w;
            } else {
                #pragma unroll
                for (int k = 0; k < 20; ++k) {
                    int gx = gx0 + k;
                    w[k] = ((unsigned)gx < (unsigned)W) ? Xr[gx] : 0.f;
                }
            }
            // out[k] = sum w[2+k .. 12+k], k=0..7 (sliding)
            float o[8], u[8];
            float s = w[2]+w[3]+w[4]+w[5]+w[6]+w[7]+w[8]+w[9]+w[10]+w[11]+w[12];
            o[0] = s;
            #pragma unroll
            for (int k = 1; k < 8; ++k) { s += w[12+k] - w[1+k]; o[k] = s; }
            float sq[20];
            #pragma unroll
            for (int k = 2; k < 20; ++k) sq[k] = w[k] * w[k];
            float s2 = sq[2]+sq[3]+sq[4]+sq[5]+sq[6]+sq[7]+sq[8]+sq[9]+sq[10]+sq[11]+sq[12];
            u[0] = s2;
            #pragma unroll
            for (int k = 1; k < 8; ++k) { s2 += sq[12+k] - sq[1+k]; u[k] = s2; }
            *(float4*)hx       = make_float4(o[0], o[1], o[2], o[3]);
            *(float4*)(hx + 4) = make_float4(o[4], o[5], o[6], o[7]);
            *(float4*)hy       = make_float4(u[0], u[1], u[2], u[3]);
            *(float4*)(hy + 4) = make_float4(u[4], u[5], u[6], u[7]);
        }
        __syncthreads();

        // ---- P4/5: vertical running 11-sums over h1 + pointwise a,b. 77 tasks
        // (cg 0..10 -> cols 4cg..4cg+3, chunk 0..6 -> A rows 6c..6c+5).
        if (tid < 77) {
            int chunk = tid / 11, cg = tid - chunk * 11;
            int r0 = chunk * 6, c4 = cg * 4;
            float mv[4];     // col-mask folded into 1/121: OOB col -> 0 -> a=b=0
            #pragma unroll
            for (int k = 0; k < 4; ++k) {
                int gx = tx0 - 5 + c4 + k;
                mv[k] = ((unsigned)gx < (unsigned)W) ? INV121 : 0.0f;
            }
            const float* hx = &S[O_H1X + c4];
            const float* hy = &S[O_H1Y + c4];
            float sx[4] = {0,0,0,0}, sy[4] = {0,0,0,0};
            #pragma unroll
            for (int d = 0; d < 10; ++d) {
                float4 a = *(const float4*)(hx + (r0 + d) * H1STR);
                float4 b = *(const float4*)(hy + (r0 + d) * H1STR);
                sx[0]+=a.x; sx[1]+=a.y; sx[2]+=a.z; sx[3]+=a.w;
                sy[0]+=b.x; sy[1]+=b.y; sy[2]+=b.z; sy[3]+=b.w;
            }
            #pragma unroll
            for (int j = 0; j < 6; ++j) {
                int q = r0 + j;
                {
                    float4 a = *(const float4*)(hx + (q + 10) * H1STR);
                    float4 b = *(const float4*)(hy + (q + 10) * H1STR);
                    sx[0]+=a.x; sx[1]+=a.y; sx[2]+=a.z; sx[3]+=a.w;
                    sy[0]+=b.x; sy[1]+=b.y; sy[2]+=b.z; sy[3]+=b.w;
                }
                int gy = ty0 - 5 + q;
                float4 av, bv;
                if ((unsigned)gy < (unsigned)W) {
                    float ao[4], bo[4];
                    #pragma unroll
                    for (int k = 0; k < 4; ++k) {
                        float mean = sx[k] * mv[k];
                        float corr = sy[k] * mv[k];
                        float var  = fmaf(-mean, mean, corr);
                        float a_   = var * __builtin_amdgcn_rcpf(var + 1e-6f);
                        ao[k] = a_;
                        bo[k] = fmaf(-a_, mean, mean);
                    }
                    av = make_float4(ao[0], ao[1], ao[2], ao[3]);
                    bv = make_float4(bo[0], bo[1], bo[2], bo[3]);
                } else {
                    av = make_float4(0.f,0.f,0.f,0.f); bv = av;
                }
                *(float4*)&S[O_A + q * ABSTR + c4] = av;
                *(float4*)&S[O_B + q * ABSTR + c4] = bv;
                {
                    float4 a = *(const float4*)(hx + q * H1STR);
                    float4 b = *(const float4*)(hy + q * H1STR);
                    sx[0]-=a.x; sx[1]-=a.y; sx[2]-=a.z; sx[3]-=a.w;
                    sy[0]-=b.x; sy[1]-=b.y; sy[2]-=b.z; sy[3]-=b.w;
                }
            }
        }
        __syncthreads();

        // ---- P6: horizontal 11-sums of a,b -> h2a,h2b. 168 tasks (r 0..41, cg 0..3 -> 8 cols).
        if (tid < 168) {
            int r = tid >> 2, cg = tid & 3;
            int j0 = cg * 8;
            const float* Ap = &S[O_A + r * ABSTR + j0];
            const float* Bp = &S[O_B + r * ABSTR + j0];
            float wa[20], wb[20];
            #pragma unroll
            for (int k = 0; k < 5; ++k) {
                float4 va = *(const float4*)(Ap + 4 * k);
                wa[4*k]=va.x; wa[4*k+1]=va.y; wa[4*k+2]=va.z; wa[4*k+3]=va.w;
                float4 vb = *(const float4*)(Bp + 4 * k);
                wb[4*k]=vb.x; wb[4*k+1]=vb.y; wb[4*k+2]=vb.z; wb[4*k+3]=vb.w;
            }
            // out[k] = sum w[k..k+10], k=0..7
            float oa[8], ob[8];
            float s = wa[0]+wa[1]+wa[2]+wa[3]+wa[4]+wa[5]+wa[6]+wa[7]+wa[8]+wa[9]+wa[10];
            oa[0] = s;
            #pragma unroll
            for (int k = 1; k < 8; ++k) { s += wa[10+k] - wa[k-1]; oa[k] = s; }
            float s2 = wb[0]+wb[1]+wb[2]+wb[3]+wb[4]+wb[5]+wb[6]+wb[7]+wb[8]+wb[9]+wb[10];
            ob[0] = s2;
            #pragma unroll
            for (int k = 1; k < 8; ++k) { s2 += wb[10+k] - wb[k-1]; ob[k] = s2; }
            float* da = &S[O_H2A + r * H2STR + j0];
            float* db = &S[O_H2B + r * H2STR + j0];
            *(float4*)da       = make_float4(oa[0], oa[1], oa[2], oa[3]);
            *(float4*)(da + 4) = make_float4(oa[4], oa[5], oa[6], oa[7]);
            *(float4*)db       = make_float4(ob[0], ob[1], ob[2], ob[3]);
            *(float4*)(db + 4) = make_float4(ob[4], ob[5], ob[6], ob[7]);
        }
        __syncthreads();

        // ---- P7/8: vertical running 11-sums over h2, finalize f, combine in F.
        // 64 tasks (cg 0..7 -> cols 4cg.., chunk 0..7 -> out rows 4c..4c+3).
        if (tid < 64) {
            int chunk = tid >> 3, cg = tid & 7;
            int r0 = chunk * 4, c4 = cg * 4;
            const float* ha = &S[O_H2A + c4];
            const float* hb = &S[O_H2B + c4];
            float sa[4] = {0,0,0,0}, sb[4] = {0,0,0,0};
            #pragma unroll
            for (int d = 0; d < 10; ++d) {
                float4 a = *(const float4*)(ha + (r0 + d) * H2STR);
                float4 b = *(const float4*)(hb + (r0 + d) * H2STR);
                sa[0]+=a.x; sa[1]+=a.y; sa[2]+=a.z; sa[3]+=a.w;
                sb[0]+=b.x; sb[1]+=b.y; sb[2]+=b.z; sb[3]+=b.w;
            }
            #pragma unroll
            for (int j = 0; j < 4; ++j) {
                int q = r0 + j;
                {
                    float4 a = *(const float4*)(ha + (q + 10) * H2STR);
                    float4 b = *(const float4*)(hb + (q + 10) * H2STR);
                    sa[0]+=a.x; sa[1]+=a.y; sa[2]+=a.z; sa[3]+=a.w;
                    sb[0]+=b.x; sb[1]+=b.y; sb[2]+=b.z; sb[3]+=b.w;
                }
                float4 xv = *(const float4*)(X + (size_t)(ty0 + q) * W + (tx0 + c4));
                float xs[4] = {xv.x, xv.y, xv.z, xv.w};
                float f[4];
                #pragma unroll
                for (int k = 0; k < 4; ++k) {
                    float t = fmaf(sa[k], xs[k], sb[k]);   // (boxa*x+boxb)*121
                    f[k] = fmaf(-t, INV121, xs[k]);        // x - q
                }
                float* Fp = &S[O_F + q * FSTR + c4];
                if (img == 0) {
                    *(float4*)Fp = make_float4(f[0], f[1], f[2], f[3]);
                } else if (img == 1) {
                    float4 t4 = *(const float4*)Fp;
                    *(float4*)Fp = make_float4(
                        fmaxf(fabsf(t4.x), fabsf(f[0])),
                        fmaxf(fabsf(t4.y), fabsf(f[1])),
                        fmaxf(fabsf(t4.z), fabsf(f[2])),
                        fmaxf(fabsf(t4.w), fabsf(f[3])));
                } else {
                    float4 t4 = *(const float4*)Fp;
                    acc += fabsf(f[0] - t4.x) + fabsf(f[1] - t4.y)
                         + fabsf(f[2] - t4.z) + fabsf(f[3] - t4.w);
                }
                {
                    float4 a = *(const float4*)(ha + q * H2STR);
                    float4 b = *(const float4*)(hb + q * H2STR);
                    sa[0]-=a.x; sa[1]-=a.y; sa[2]-=a.z; sa[3]-=a.w;
                    sb[0]-=b.x; sb[1]-=b.y; sb[2]-=b.z; sb[3]-=b.w;
                }
            }
        }
    } // img loop

    // block reduction (acc nonzero only for tid<64; all threads participate)
    #pragma unroll
    for (int off = 32; off > 0; off >>= 1) acc += __shfl_down(acc, off);
    __syncthreads();
    if ((tid & 63) == 0) S[tid >> 6] = acc;
    __syncthreads();
    if (tid == 0) {
        float blocksum = S[0] + S[1] + S[2] + S[3];
        partials[((blockIdx.z * NBLK_Y) + blockIdx.y) * NBLK_X + blockIdx.x] = blocksum;
    }
}

__global__ __launch_bounds__(256) void sgf_final_reduce(
    const float* __restrict__ partials, float* __restrict__ out)
{
    __shared__ double sd[256];
    int tid = threadIdx.x;
    double s = 0.0;
    for (int i = tid; i < NPARTIALS; i += 256) s += (double)partials[i];
    sd[tid] = s;
    __syncthreads();
    for (int off = 128; off > 0; off >>= 1) {
        if (tid < off) sd[tid] += sd[tid + off];
        __syncthreads();
    }
    if (tid == 0) out[0] = (float)(sd[0] * (1.0 / TOTAL_ELEMS));
}

extern "C" void kernel_launch(void* const* d_in, const int* in_sizes, int n_in,
                              void* d_out, int out_size, void* d_ws, size_t ws_size,
                              hipStream_t stream) {
    const float* gen = (const float*)d_in[0];
    const float* ir  = (const float*)d_in[1];
    const float* vi  = (const float*)d_in[2];
    float* partials = (float*)d_ws;   // 6144 floats = 24 KB

    dim3 grid(NBLK_X, NBLK_Y, NPLANES);
    sgf_loss_kernel<<<grid, dim3(256), 0, stream>>>(gen, ir, vi, partials);
    sgf_final_reduce<<<1, dim3(256), 0, stream>>>(partials, (float*)d_out);
}